// Round 1
// baseline (13175.777 us; speedup 1.0000x reference)
//
#include <hip/hip_runtime.h>
#include <hip/hip_bf16.h>
#include <math.h>

#define BB 2
#define LL 8192
#define DD 512
#define NLAYER 8
#define TD 1536   // 3*D
#define HD 2048   // 4*D
#define NFFT 16384
#define NH 8192   // NFFT/2
#define BLD (BB*LL*DD)

// ---------------- twiddle table: tw[k] = exp(-2*pi*i*k/NFFT), k in [0,NH) ----
__global__ void twiddle_kernel(float* twf) {
    int k = blockIdx.x * 256 + threadIdx.x;
    if (k < NH) {
        double ang = -2.0 * M_PI * (double)k / (double)NFFT;
        twf[2 * k]     = (float)cos(ang);
        twf[2 * k + 1] = (float)sin(ang);
    }
}

// ---------------- embedding ------------------------------------------------
__global__ void embed_kernel(const int* __restrict__ ids,
                             const float* __restrict__ emb,
                             float* __restrict__ u) {
    int i = blockIdx.x * 256 + threadIdx.x;
    if (i < BLD) {
        int row = i >> 9;          // / D
        int d   = i & (DD - 1);
        u[i] = emb[ids[row] * DD + d];
    }
}

// ---------------- layernorm (row length 512), one block per row ------------
__global__ __launch_bounds__(128)
void ln_kernel(const float* __restrict__ x, float* __restrict__ out,
               const float* __restrict__ g, const float* __restrict__ b) {
    int row = blockIdx.x;
    const float4* xr = (const float4*)(x + (size_t)row * DD);
    int t = threadIdx.x;  // 0..127, 4 floats each
    float4 v = xr[t];
    float s  = v.x + v.y + v.z + v.w;
    float ss = v.x * v.x + v.y * v.y + v.z * v.z + v.w * v.w;
    for (int off = 32; off; off >>= 1) {
        s  += __shfl_down(s, off);
        ss += __shfl_down(ss, off);
    }
    __shared__ float sm[4];
    if ((t & 63) == 0) { sm[(t >> 6) * 2] = s; sm[(t >> 6) * 2 + 1] = ss; }
    __syncthreads();
    float S = sm[0] + sm[2], SS = sm[1] + sm[3];
    float mu  = S * (1.0f / DD);
    float var = SS * (1.0f / DD) - mu * mu;
    float rs  = rsqrtf(var + 1e-5f);
    float4 gg = ((const float4*)g)[t];
    float4 bb = ((const float4*)b)[t];
    float4 o;
    o.x = (v.x - mu) * rs * gg.x + bb.x;
    o.y = (v.y - mu) * rs * gg.y + bb.y;
    o.z = (v.z - mu) * rs * gg.z + bb.z;
    o.w = (v.w - mu) * rs * gg.w + bb.w;
    ((float4*)(out + (size_t)row * DD))[t] = o;
}

// ---------------- gelu (JAX default tanh approximation) --------------------
__device__ __forceinline__ float gelu_f(float x) {
    float x3 = x * x * x;
    float t  = tanhf(0.79788456080286541f * (x + 0.044715f * x3));
    return 0.5f * x * (1.0f + t);
}

// ---------------- tiled f32 GEMM: C[M,N] (+)= A @ W + bias -----------------
// A: row-major [M,K] (A_COL=false) or col-major [K,M] (A_COL=true, lda=M)
// W: row-major [K,N].  blockIdx.z = batch (strides in elements).
template<bool A_COL, bool ACCUM, bool GELU>
__global__ __launch_bounds__(256)
void gemm_kernel(const float* __restrict__ A, const float* __restrict__ Wm,
                 const float* __restrict__ bias, float* __restrict__ C,
                 int M, int N, int K, long batchStrideA, long batchStrideC) {
    constexpr int BK = 16;
    __shared__ __align__(16) float As[BK][128];
    __shared__ __align__(16) float Bs[BK][128];
    const float* Ab = A + (size_t)blockIdx.z * batchStrideA;
    float*       Cb = C + (size_t)blockIdx.z * batchStrideC;
    int m0 = blockIdx.y * 128, n0 = blockIdx.x * 128;
    int tid = threadIdx.x;
    int tx = tid & 15, ty = tid >> 4;
    float acc[8][8] = {};
    for (int k0 = 0; k0 < K; k0 += BK) {
        if (!A_COL) {
            int kq = tid & 3, mr = tid >> 2;
#pragma unroll
            for (int i = 0; i < 2; i++) {
                int m = mr + i * 64;
                float4 a4 = *(const float4*)&Ab[(size_t)(m0 + m) * K + k0 + kq * 4];
                As[kq * 4 + 0][m] = a4.x; As[kq * 4 + 1][m] = a4.y;
                As[kq * 4 + 2][m] = a4.z; As[kq * 4 + 3][m] = a4.w;
            }
        } else {
            int mm = tid & 31, kr = tid >> 5;
#pragma unroll
            for (int i = 0; i < 2; i++) {
                int kk = kr + i * 8;
                float4 a4 = *(const float4*)&Ab[(size_t)(k0 + kk) * M + m0 + mm * 4];
                *(float4*)&As[kk][mm * 4] = a4;
            }
        }
        {
            int nn = tid & 31, kr = tid >> 5;
#pragma unroll
            for (int i = 0; i < 2; i++) {
                int kk = kr + i * 8;
                float4 b4 = *(const float4*)&Wm[(size_t)(k0 + kk) * N + n0 + nn * 4];
                *(float4*)&Bs[kk][nn * 4] = b4;
            }
        }
        __syncthreads();
#pragma unroll
        for (int k = 0; k < BK; k++) {
            float4 a0 = *(float4*)&As[k][ty * 8];
            float4 a1 = *(float4*)&As[k][ty * 8 + 4];
            float4 b0 = *(float4*)&Bs[k][tx * 8];
            float4 b1 = *(float4*)&Bs[k][tx * 8 + 4];
            float av[8] = {a0.x, a0.y, a0.z, a0.w, a1.x, a1.y, a1.z, a1.w};
            float bv[8] = {b0.x, b0.y, b0.z, b0.w, b1.x, b1.y, b1.z, b1.w};
#pragma unroll
            for (int i = 0; i < 8; i++)
#pragma unroll
                for (int j = 0; j < 8; j++) acc[i][j] += av[i] * bv[j];
        }
        __syncthreads();
    }
#pragma unroll
    for (int i = 0; i < 8; i++) {
        int m = m0 + ty * 8 + i;
#pragma unroll
        for (int j = 0; j < 8; j += 4) {
            int n = n0 + tx * 8 + j;
            float4 r = {acc[i][j], acc[i][j + 1], acc[i][j + 2], acc[i][j + 3]};
            float4 bb = *(const float4*)&bias[n];
            r.x += bb.x; r.y += bb.y; r.z += bb.z; r.w += bb.w;
            if (GELU) { r.x = gelu_f(r.x); r.y = gelu_f(r.y); r.z = gelu_f(r.z); r.w = gelu_f(r.w); }
            float* cp = &Cb[(size_t)m * N + n];
            if (ACCUM) {
                float4 c0 = *(float4*)cp;
                r.x += c0.x; r.y += c0.y; r.z += c0.z; r.w += c0.w;
            }
            *(float4*)cp = r;
        }
    }
}

// ---------------- short conv (k=3 causal, depthwise) + gating + transpose --
// p: [B, L, 3D] row-major.  Outputs channel-major [B, D, L]:
//   vg  = conv(v)*conv(x1),  x2s = conv(x2)
__global__ __launch_bounds__(256)
void conv_gate_kernel(const float* __restrict__ p, const float* __restrict__ cw,
                      const float* __restrict__ cb, float* __restrict__ vg,
                      float* __restrict__ x2s) {
    __shared__ float tvg[64][65];
    __shared__ float tx2[64][65];
    int b = blockIdx.z, c0 = blockIdx.y * 64, l0 = blockIdx.x * 64;
    int tc = threadIdx.x & 63, tr = threadIdx.x >> 6;  // tr in 0..3
    const float* pb = p + (size_t)b * LL * TD;
    int cx2 = c0 + tc;
    int cx1 = DD + c0 + tc;
    int cv  = 2 * DD + c0 + tc;
    float w20 = cw[cx2 * 3], w21 = cw[cx2 * 3 + 1], w22 = cw[cx2 * 3 + 2], bx2 = cb[cx2];
    float w10 = cw[cx1 * 3], w11 = cw[cx1 * 3 + 1], w12 = cw[cx1 * 3 + 2], bx1 = cb[cx1];
    float wv0 = cw[cv * 3],  wv1 = cw[cv * 3 + 1],  wv2 = cw[cv * 3 + 2],  bv  = cb[cv];
    for (int r = tr; r < 64; r += 4) {
        int l = l0 + r;
        size_t o0 = (size_t)l * TD;
        float p2a = (l >= 2) ? pb[o0 - 2 * TD + cx2] : 0.f;
        float p1a = (l >= 1) ? pb[o0 - TD + cx2] : 0.f;
        float p0a = pb[o0 + cx2];
        float p2b = (l >= 2) ? pb[o0 - 2 * TD + cx1] : 0.f;
        float p1b = (l >= 1) ? pb[o0 - TD + cx1] : 0.f;
        float p0b = pb[o0 + cx1];
        float p2c = (l >= 2) ? pb[o0 - 2 * TD + cv] : 0.f;
        float p1c = (l >= 1) ? pb[o0 - TD + cv] : 0.f;
        float p0c = pb[o0 + cv];
        float x2v = w20 * p2a + w21 * p1a + w22 * p0a + bx2;
        float x1v = w10 * p2b + w11 * p1b + w12 * p0b + bx1;
        float vv  = wv0 * p2c + wv1 * p1c + wv2 * p0c + bv;
        tx2[r][tc] = x2v;
        tvg[r][tc] = vv * x1v;
    }
    __syncthreads();
    for (int r = tr; r < 64; r += 4) {
        size_t o = ((size_t)b * DD + c0 + r) * LL + l0 + tc;
        vg[o]  = tvg[tc][r];
        x2s[o] = tx2[tc][r];
    }
}

// ---------------- FFT helpers (radix-2, 16384-pt complex in LDS) -----------
// Forward DIF: natural in -> bit-reversed out, twiddles e^{-i...}
__device__ __forceinline__ void fft_forward(float2* ld, const float2* __restrict__ tw, int tid) {
    for (int s = 0; s < 14; s++) {
        int half = NFFT >> (s + 1);
        __syncthreads();
        for (int m = tid; m < NFFT / 2; m += 512) {
            int j  = m & (half - 1);
            int a  = ((m >> (13 - s)) << (14 - s)) + j;
            int bi = a + half;
            float2 A = ld[a], Bv = ld[bi];
            float2 w = tw[j << s];
            float tr_ = A.x - Bv.x, ti_ = A.y - Bv.y;
            ld[a]  = make_float2(A.x + Bv.x, A.y + Bv.y);
            ld[bi] = make_float2(tr_ * w.x - ti_ * w.y, tr_ * w.y + ti_ * w.x);
        }
    }
    __syncthreads();
}

// Inverse DIT: bit-reversed in -> natural out, conjugated twiddles (no 1/N)
__device__ __forceinline__ void fft_inverse(float2* ld, const float2* __restrict__ tw, int tid) {
    for (int s = 0; s < 14; s++) {
        int half = 1 << s;
        __syncthreads();
        for (int m = tid; m < NFFT / 2; m += 512) {
            int j  = m & (half - 1);
            int a  = ((m >> s) << (s + 1)) + j;
            int bi = a + half;
            float2 A = ld[a], Bv = ld[bi];
            float2 w = tw[j << (13 - s)];
            // B * conj(w)
            float tx_ = Bv.x * w.x + Bv.y * w.y;
            float ty_ = Bv.y * w.x - Bv.x * w.y;
            ld[a]  = make_float2(A.x + tx_, A.y + ty_);
            ld[bi] = make_float2(A.x - tx_, A.y - ty_);
        }
    }
    __syncthreads();
}

// ---------------- per-channel filter FFT -----------------------------------
__global__ __launch_bounds__(512)
void hf_kernel(const float* __restrict__ h, float* __restrict__ Hf,
               const float* __restrict__ twf) {
    __shared__ float2 ld[NFFT];  // 128 KiB
    int c = blockIdx.x;
    const float* hc = h + (size_t)c * LL;
    const float2* tw = (const float2*)twf;
    for (int i = threadIdx.x; i < LL; i += 512) ld[i] = make_float2(hc[i], 0.f);
    for (int i = LL + threadIdx.x; i < NFFT; i += 512) ld[i] = make_float2(0.f, 0.f);
    fft_forward(ld, tw, threadIdx.x);
    float2* out = (float2*)Hf + (size_t)c * NFFT;
    for (int i = threadIdx.x; i < NFFT; i += 512) out[i] = ld[i];
}

// ---------------- FFT convolution + bias-skip + output gate ----------------
// per (b,c): yg[b,c,:] = (irfft(fft(vg)*Hf)[:L] + vg*Db[c]) * x2s[b,c,:]
__global__ __launch_bounds__(512)
void fftconv_kernel(const float* __restrict__ vg, const float* __restrict__ x2s,
                    const float* __restrict__ Hf, const float* __restrict__ Db,
                    const float* __restrict__ twf, float* __restrict__ yg) {
    __shared__ float2 ld[NFFT];  // 128 KiB
    int bc = blockIdx.x;          // b*D + c
    int c  = bc & (DD - 1);
    const float* v = vg + (size_t)bc * LL;
    const float2* tw = (const float2*)twf;
    for (int i = threadIdx.x; i < LL; i += 512) ld[i] = make_float2(v[i], 0.f);
    for (int i = LL + threadIdx.x; i < NFFT; i += 512) ld[i] = make_float2(0.f, 0.f);
    fft_forward(ld, tw, threadIdx.x);
    const float2* Hc = (const float2*)Hf + (size_t)c * NFFT;
    for (int i = threadIdx.x; i < NFFT; i += 512) {
        float2 A = ld[i], Bv = Hc[i];
        ld[i] = make_float2(A.x * Bv.x - A.y * Bv.y, A.x * Bv.y + A.y * Bv.x);
    }
    fft_inverse(ld, tw, threadIdx.x);
    float dbc = Db[c];
    const float* x2 = x2s + (size_t)bc * LL;
    float* out = yg + (size_t)bc * LL;
    for (int i = threadIdx.x; i < LL; i += 512) {
        float yv = ld[i].x * (1.0f / NFFT) + v[i] * dbc;
        out[i] = yv * x2[i];
    }
}

// ---------------------------------------------------------------------------
extern "C" void kernel_launch(void* const* d_in, const int* in_sizes, int n_in,
                              void* d_out, int out_size, void* d_ws, size_t ws_size,
                              hipStream_t stream) {
    const int*   ids   = (const int*)  d_in[0];
    const float* emb   = (const float*)d_in[1];
    const float* ln1_g = (const float*)d_in[2];
    const float* ln1_b = (const float*)d_in[3];
    const float* Win   = (const float*)d_in[4];
    const float* bin_  = (const float*)d_in[5];
    const float* convw = (const float*)d_in[6];
    const float* convb = (const float*)d_in[7];
    const float* hflt  = (const float*)d_in[8];
    const float* Db    = (const float*)d_in[9];
    const float* Wout  = (const float*)d_in[10];
    const float* bout  = (const float*)d_in[11];
    const float* ln2_g = (const float*)d_in[12];
    const float* ln2_b = (const float*)d_in[13];
    const float* W1    = (const float*)d_in[14];
    const float* b1    = (const float*)d_in[15];
    const float* W2    = (const float*)d_in[16];
    const float* b2    = (const float*)d_in[17];
    const float* lnf_g = (const float*)d_in[18];
    const float* lnf_b = (const float*)d_in[19];

    float* ws  = (float*)d_ws;
    float* u   = ws;                       // B*L*D
    float* z   = u + BLD;                  // B*L*D
    float* ph  = z + BLD;                  // B*L*4D (shared p / hmid)
    float* vg  = ph + (size_t)BB * LL * HD;   // B*D*L
    float* x2s = vg + BLD;                 // B*D*L
    float* yg  = x2s + BLD;                // B*D*L
    float* Hf  = yg + BLD;                 // 2*D*NFFT
    float* tw  = Hf + (size_t)2 * DD * NFFT;  // 2*NH

    twiddle_kernel<<<(NH + 255) / 256, 256, 0, stream>>>(tw);
    embed_kernel<<<(BLD + 255) / 256, 256, 0, stream>>>(ids, emb, u);

    for (int l = 0; l < NLAYER; l++) {
        ln_kernel<<<BB * LL, 128, 0, stream>>>(u, z, ln1_g + l * DD, ln1_b + l * DD);

        gemm_kernel<false, false, false><<<dim3(TD / 128, (BB * LL) / 128, 1), 256, 0, stream>>>(
            z, Win + (size_t)l * DD * TD, bin_ + (size_t)l * TD, ph,
            BB * LL, TD, DD, 0, 0);

        conv_gate_kernel<<<dim3(LL / 64, DD / 64, BB), 256, 0, stream>>>(
            ph, convw + (size_t)l * TD * 3, convb + (size_t)l * TD, vg, x2s);

        hf_kernel<<<DD, 512, 0, stream>>>(hflt + (size_t)l * DD * LL, Hf, tw);

        fftconv_kernel<<<BB * DD, 512, 0, stream>>>(vg, x2s, Hf, Db + (size_t)l * DD, tw, yg);

        gemm_kernel<true, true, false><<<dim3(DD / 128, LL / 128, BB), 256, 0, stream>>>(
            yg, Wout + (size_t)l * DD * DD, bout + (size_t)l * DD, u,
            LL, DD, DD, (long)DD * LL, (long)LL * DD);

        ln_kernel<<<BB * LL, 128, 0, stream>>>(u, z, ln2_g + l * DD, ln2_b + l * DD);

        gemm_kernel<false, false, true><<<dim3(HD / 128, (BB * LL) / 128, 1), 256, 0, stream>>>(
            z, W1 + (size_t)l * DD * HD, b1 + (size_t)l * HD, ph,
            BB * LL, HD, DD, 0, 0);

        gemm_kernel<false, true, false><<<dim3(DD / 128, (BB * LL) / 128, 1), 256, 0, stream>>>(
            ph, W2 + (size_t)l * HD * DD, b2 + (size_t)l * DD, u,
            BB * LL, DD, HD, 0, 0);
    }

    ln_kernel<<<BB * LL, 128, 0, stream>>>(u, (float*)d_out, lnf_g, lnf_b);
}

// Round 3
// 6971.263 us; speedup vs baseline: 1.8900x; 1.8900x over previous
//
#include <hip/hip_runtime.h>
#include <hip/hip_bf16.h>
#include <math.h>

#define BB 2
#define LL 8192
#define DD 512
#define NLAYER 8
#define TD 1536   // 3*D
#define HD 2048   // 4*D
#define NFFT 16384
#define NH 8192   // NFFT/2
#define BLD (BB*LL*DD)
#define BLH ((size_t)BB*LL*HD)

typedef unsigned short u16;
typedef unsigned int   u32;
typedef __bf16 bf16x8 __attribute__((ext_vector_type(8)));
typedef float  f32x4  __attribute__((ext_vector_type(4)));

__device__ __forceinline__ u16 f2bf(float f) {
    union { float f; u32 u; } v; v.f = f;
    u32 r = v.u + 0x7FFF + ((v.u >> 16) & 1);   // RNE
    return (u16)(r >> 16);
}
__device__ __forceinline__ float bf2f(u16 h) {
    union { u32 u; float f; } v; v.u = (u32)h << 16; return v.f;
}

__device__ __forceinline__ void async_g2l_16(const u16* g, u16* l) {
    __builtin_amdgcn_global_load_lds(
        (const __attribute__((address_space(1))) void*)g,
        (__attribute__((address_space(3))) void*)l,
        16, 0, 0);
}

// ---------------- twiddle table: tw[k] = exp(-2*pi*i*k/NFFT) ----------------
__global__ void twiddle_kernel(float* twf) {
    int k = blockIdx.x * 256 + threadIdx.x;
    if (k < NH) {
        double ang = -2.0 * M_PI * (double)k / (double)NFFT;
        twf[2 * k]     = (float)cos(ang);
        twf[2 * k + 1] = (float)sin(ang);
    }
}

// ---------------- embedding ------------------------------------------------
__global__ void embed_kernel(const int* __restrict__ ids,
                             const float* __restrict__ emb,
                             float* __restrict__ u) {
    int i = blockIdx.x * 256 + threadIdx.x;
    if (i < BLD) {
        int row = i >> 9;
        int d   = i & (DD - 1);
        u[i] = emb[ids[row] * DD + d];
    }
}

// ------------- weight prep: f32 [K,N] -> bf16 hi/lo [N,K] -------------------
__global__ __launch_bounds__(256)
void wprep_kernel(const float* __restrict__ W, u16* __restrict__ WtH,
                  u16* __restrict__ WtL, int K, int N, long srcStride, long dstStride) {
    __shared__ float t[64][65];
    const float* src = W + (size_t)blockIdx.z * srcStride;
    u16* dsth = WtH + (size_t)blockIdx.z * dstStride;
    u16* dstl = WtL + (size_t)blockIdx.z * dstStride;
    int n0 = blockIdx.x * 64, k0 = blockIdx.y * 64;
    int tc = threadIdx.x & 63, tr = threadIdx.x >> 6;
    for (int r = tr; r < 64; r += 4)
        t[r][tc] = src[(size_t)(k0 + r) * N + n0 + tc];
    __syncthreads();
    for (int r = tr; r < 64; r += 4) {
        float v = t[tc][r];
        u16 h = f2bf(v);
        dsth[(size_t)(n0 + r) * K + k0 + tc] = h;
        dstl[(size_t)(n0 + r) * K + k0 + tc] = f2bf(v - bf2f(h));
    }
}

// ---------------- layernorm (row length 512) -------------------------------
// MODE 0: f32 out.  MODE 1: bf16 hi/lo planes.
template<int MODE>
__global__ __launch_bounds__(128)
void ln_kernel(const float* __restrict__ x, void* __restrict__ out,
               void* __restrict__ outL,
               const float* __restrict__ g, const float* __restrict__ b) {
    int row = blockIdx.x;
    const float4* xr = (const float4*)(x + (size_t)row * DD);
    int t = threadIdx.x;
    float4 v = xr[t];
    float s  = v.x + v.y + v.z + v.w;
    float ss = v.x * v.x + v.y * v.y + v.z * v.z + v.w * v.w;
    for (int off = 32; off; off >>= 1) {
        s  += __shfl_down(s, off);
        ss += __shfl_down(ss, off);
    }
    __shared__ float sm[4];
    if ((t & 63) == 0) { sm[(t >> 6) * 2] = s; sm[(t >> 6) * 2 + 1] = ss; }
    __syncthreads();
    float S = sm[0] + sm[2], SS = sm[1] + sm[3];
    float mu  = S * (1.0f / DD);
    float var = SS * (1.0f / DD) - mu * mu;
    float rs  = rsqrtf(var + 1e-5f);
    float4 gg = ((const float4*)g)[t];
    float4 bb = ((const float4*)b)[t];
    float o[4];
    o[0] = (v.x - mu) * rs * gg.x + bb.x;
    o[1] = (v.y - mu) * rs * gg.y + bb.y;
    o[2] = (v.z - mu) * rs * gg.z + bb.z;
    o[3] = (v.w - mu) * rs * gg.w + bb.w;
    if (MODE == 1) {
        u16 h[4], lo[4];
#pragma unroll
        for (int i = 0; i < 4; i++) {
            h[i]  = f2bf(o[i]);
            lo[i] = f2bf(o[i] - bf2f(h[i]));
        }
        uint2 ph, pl;
        ph.x = (u32)h[0] | ((u32)h[1] << 16);  ph.y = (u32)h[2] | ((u32)h[3] << 16);
        pl.x = (u32)lo[0] | ((u32)lo[1] << 16); pl.y = (u32)lo[2] | ((u32)lo[3] << 16);
        ((uint2*)((u16*)out  + (size_t)row * DD))[t] = ph;
        ((uint2*)((u16*)outL + (size_t)row * DD))[t] = pl;
    } else {
        float4 of = {o[0], o[1], o[2], o[3]};
        ((float4*)((float*)out + (size_t)row * DD))[t] = of;
    }
}

// ---------------- gelu (tanh approximation, JAX default) -------------------
__device__ __forceinline__ float gelu_f(float x) {
    float x3 = x * x * x;
    float t  = tanhf(0.79788456080286541f * (x + 0.044715f * x3));
    return 0.5f * x * (1.0f + t);
}

// ------- compensated bf16 MFMA GEMM: C = (Ah+Al) @ (Bh+Bl)^T + bias --------
// 3-pass split: ah*bh + al*bh + ah*bl (lo*lo dropped, ~2^-18 rel).
// 128x128 tile, BK=32, 4 waves (2x2), 4x4 16x16x32 frags/wave.
// OUT 0: store f32.  OUT 1: store bf16 hi/lo planes.  OUT 2: accumulate f32.
template<int OUT, bool GELU>
__global__ __launch_bounds__(256)
void mfma_gemm3(const u16* __restrict__ Ah, const u16* __restrict__ Al,
                const u16* __restrict__ Bh, const u16* __restrict__ Bl,
                const float* __restrict__ bias,
                float* __restrict__ Cf, u16* __restrict__ Ch, u16* __restrict__ Cl,
                int M, int N, int K) {
    __shared__ u16 AsH[128 * 32];
    __shared__ u16 AsL[128 * 32];
    __shared__ u16 BsH[128 * 32];
    __shared__ u16 BsL[128 * 32];
    int m0 = blockIdx.y * 128, n0 = blockIdx.x * 128;
    int tid = threadIdx.x;
    int w = tid >> 6, l = tid & 63;
    int wr = w >> 1, wc = w & 1;

    int ch0 = w * 2, ch1 = ch0 + 1;
    size_t offA0 = (size_t)(m0 + ch0 * 16 + (l >> 2)) * K + (l & 3) * 8;
    size_t offA1 = (size_t)(m0 + ch1 * 16 + (l >> 2)) * K + (l & 3) * 8;
    size_t offB0 = (size_t)(n0 + ch0 * 16 + (l >> 2)) * K + (l & 3) * 8;
    size_t offB1 = (size_t)(n0 + ch1 * 16 + (l >> 2)) * K + (l & 3) * 8;

    f32x4 acc[4][4] = {};
    int arow = wr * 64 + (l & 15);
    int brow = wc * 64 + (l & 15);
    int kc   = (l >> 4) * 8;

    for (int k0 = 0; k0 < K; k0 += 32) {
        async_g2l_16(Ah + offA0 + k0, &AsH[ch0 * 512]);
        async_g2l_16(Ah + offA1 + k0, &AsH[ch1 * 512]);
        async_g2l_16(Al + offA0 + k0, &AsL[ch0 * 512]);
        async_g2l_16(Al + offA1 + k0, &AsL[ch1 * 512]);
        async_g2l_16(Bh + offB0 + k0, &BsH[ch0 * 512]);
        async_g2l_16(Bh + offB1 + k0, &BsH[ch1 * 512]);
        async_g2l_16(Bl + offB0 + k0, &BsL[ch0 * 512]);
        async_g2l_16(Bl + offB1 + k0, &BsL[ch1 * 512]);
        __syncthreads();
        bf16x8 ah[4], al[4], bh[4], bl[4];
#pragma unroll
        for (int i = 0; i < 4; i++) {
            ah[i] = *(const bf16x8*)&AsH[(arow + i * 16) * 32 + kc];
            al[i] = *(const bf16x8*)&AsL[(arow + i * 16) * 32 + kc];
            bh[i] = *(const bf16x8*)&BsH[(brow + i * 16) * 32 + kc];
            bl[i] = *(const bf16x8*)&BsL[(brow + i * 16) * 32 + kc];
        }
#pragma unroll
        for (int mi = 0; mi < 4; mi++)
#pragma unroll
            for (int ni = 0; ni < 4; ni++) {
                acc[mi][ni] = __builtin_amdgcn_mfma_f32_16x16x32_bf16(
                    ah[mi], bh[ni], acc[mi][ni], 0, 0, 0);
                acc[mi][ni] = __builtin_amdgcn_mfma_f32_16x16x32_bf16(
                    al[mi], bh[ni], acc[mi][ni], 0, 0, 0);
                acc[mi][ni] = __builtin_amdgcn_mfma_f32_16x16x32_bf16(
                    ah[mi], bl[ni], acc[mi][ni], 0, 0, 0);
            }
        __syncthreads();
    }

    // epilogue: C/D map col=lane&15, row=(lane>>4)*4+reg
    int lr = l >> 4, lc = l & 15;
#pragma unroll
    for (int mi = 0; mi < 4; mi++) {
#pragma unroll
        for (int ni = 0; ni < 4; ni++) {
            int col = n0 + wc * 64 + ni * 16 + lc;
            float bv = bias[col];
            int rowb = m0 + wr * 64 + mi * 16 + lr * 4;
#pragma unroll
            for (int r = 0; r < 4; r++) {
                float v = acc[mi][ni][r] + bv;
                if (GELU) v = gelu_f(v);
                size_t off = (size_t)(rowb + r) * N + col;
                if (OUT == 0) {
                    Cf[off] = v;
                } else if (OUT == 1) {
                    u16 h = f2bf(v);
                    Ch[off] = h;
                    Cl[off] = f2bf(v - bf2f(h));
                } else {
                    Cf[off] += v;
                }
            }
        }
    }
}

// ---------------- short conv (k=3 causal) + gating + transpose -------------
// p: f32 [B, L, 3D].  Outputs f32 channel-major [B, D, L].
__global__ __launch_bounds__(256)
void conv_gate_kernel(const float* __restrict__ p, const float* __restrict__ cw,
                      const float* __restrict__ cb, float* __restrict__ vg,
                      float* __restrict__ x2s) {
    __shared__ float tvg[64][65];
    __shared__ float tx2[64][65];
    int b = blockIdx.z, c0 = blockIdx.y * 64, l0 = blockIdx.x * 64;
    int tc = threadIdx.x & 63, tr = threadIdx.x >> 6;
    const float* pb = p + (size_t)b * LL * TD;
    int cx2 = c0 + tc;
    int cx1 = DD + c0 + tc;
    int cv  = 2 * DD + c0 + tc;
    float w20 = cw[cx2 * 3], w21 = cw[cx2 * 3 + 1], w22 = cw[cx2 * 3 + 2], bx2 = cb[cx2];
    float w10 = cw[cx1 * 3], w11 = cw[cx1 * 3 + 1], w12 = cw[cx1 * 3 + 2], bx1 = cb[cx1];
    float wv0 = cw[cv * 3],  wv1 = cw[cv * 3 + 1],  wv2 = cw[cv * 3 + 2],  bv  = cb[cv];
    for (int r = tr; r < 64; r += 4) {
        int l = l0 + r;
        size_t o0 = (size_t)l * TD;
        float p2a = (l >= 2) ? pb[o0 - 2 * TD + cx2] : 0.f;
        float p1a = (l >= 1) ? pb[o0 - TD + cx2] : 0.f;
        float p0a = pb[o0 + cx2];
        float p2b = (l >= 2) ? pb[o0 - 2 * TD + cx1] : 0.f;
        float p1b = (l >= 1) ? pb[o0 - TD + cx1] : 0.f;
        float p0b = pb[o0 + cx1];
        float p2c = (l >= 2) ? pb[o0 - 2 * TD + cv] : 0.f;
        float p1c = (l >= 1) ? pb[o0 - TD + cv] : 0.f;
        float p0c = pb[o0 + cv];
        float x2v = w20 * p2a + w21 * p1a + w22 * p0a + bx2;
        float x1v = w10 * p2b + w11 * p1b + w12 * p0b + bx1;
        float vv  = wv0 * p2c + wv1 * p1c + wv2 * p0c + bv;
        tx2[r][tc] = x2v;
        tvg[r][tc] = vv * x1v;
    }
    __syncthreads();
    for (int r = tr; r < 64; r += 4) {
        size_t o = ((size_t)b * DD + c0 + r) * LL + l0 + tc;
        vg[o]  = tvg[tc][r];
        x2s[o] = tx2[tc][r];
    }
}

// -------- y transpose: f32 [B,D,L] -> bf16 hi/lo [B*L, D] ------------------
__global__ __launch_bounds__(256)
void ytr_kernel(const float* __restrict__ yg, u16* __restrict__ yh,
                u16* __restrict__ yl) {
    __shared__ float t[64][65];
    int b = blockIdx.z, c0 = blockIdx.y * 64, l0 = blockIdx.x * 64;
    int tc = threadIdx.x & 63, tr = threadIdx.x >> 6;
    for (int r = tr; r < 64; r += 4)
        t[r][tc] = yg[((size_t)b * DD + c0 + r) * LL + l0 + tc];
    __syncthreads();
    for (int r = tr; r < 64; r += 4) {
        float v = t[tc][r];
        u16 h = f2bf(v);
        size_t o = ((size_t)(b * LL + l0 + r)) * DD + c0 + tc;
        yh[o] = h;
        yl[o] = f2bf(v - bf2f(h));
    }
}

// ---------------- FFT helpers (radix-2, 16384-pt complex in LDS) -----------
__device__ __forceinline__ void fft_forward(float2* ld, const float2* __restrict__ tw, int tid) {
    for (int s = 0; s < 14; s++) {
        int half = NFFT >> (s + 1);
        __syncthreads();
        for (int m = tid; m < NFFT / 2; m += 512) {
            int j  = m & (half - 1);
            int a  = ((m >> (13 - s)) << (14 - s)) + j;
            int bi = a + half;
            float2 A = ld[a], Bv = ld[bi];
            float2 w = tw[j << s];
            float tr_ = A.x - Bv.x, ti_ = A.y - Bv.y;
            ld[a]  = make_float2(A.x + Bv.x, A.y + Bv.y);
            ld[bi] = make_float2(tr_ * w.x - ti_ * w.y, tr_ * w.y + ti_ * w.x);
        }
    }
    __syncthreads();
}

__device__ __forceinline__ void fft_inverse(float2* ld, const float2* __restrict__ tw, int tid) {
    for (int s = 0; s < 14; s++) {
        int half = 1 << s;
        __syncthreads();
        for (int m = tid; m < NFFT / 2; m += 512) {
            int j  = m & (half - 1);
            int a  = ((m >> s) << (s + 1)) + j;
            int bi = a + half;
            float2 A = ld[a], Bv = ld[bi];
            float2 w = tw[j << (13 - s)];
            float tx_ = Bv.x * w.x + Bv.y * w.y;
            float ty_ = Bv.y * w.x - Bv.x * w.y;
            ld[a]  = make_float2(A.x + tx_, A.y + ty_);
            ld[bi] = make_float2(A.x - tx_, A.y - ty_);
        }
    }
    __syncthreads();
}

// ---------------- per-channel filter FFT -----------------------------------
__global__ __launch_bounds__(512)
void hf_kernel(const float* __restrict__ h, float* __restrict__ Hf,
               const float* __restrict__ twf) {
    __shared__ float2 ld[NFFT];  // 128 KiB
    int c = blockIdx.x;
    const float* hc = h + (size_t)c * LL;
    const float2* tw = (const float2*)twf;
    for (int i = threadIdx.x; i < LL; i += 512) ld[i] = make_float2(hc[i], 0.f);
    for (int i = LL + threadIdx.x; i < NFFT; i += 512) ld[i] = make_float2(0.f, 0.f);
    fft_forward(ld, tw, threadIdx.x);
    float2* out = (float2*)Hf + (size_t)c * NFFT;
    for (int i = threadIdx.x; i < NFFT; i += 512) out[i] = ld[i];
}

// ---------------- FFT convolution + bias-skip + output gate ----------------
__global__ __launch_bounds__(512)
void fftconv_kernel(const float* __restrict__ vg, const float* __restrict__ x2s,
                    const float* __restrict__ Hf, const float* __restrict__ Db,
                    const float* __restrict__ twf, float* __restrict__ yg) {
    __shared__ float2 ld[NFFT];  // 128 KiB
    int bc = blockIdx.x;
    int c  = bc & (DD - 1);
    const float* v = vg + (size_t)bc * LL;
    const float2* tw = (const float2*)twf;
    for (int i = threadIdx.x; i < LL; i += 512) ld[i] = make_float2(v[i], 0.f);
    for (int i = LL + threadIdx.x; i < NFFT; i += 512) ld[i] = make_float2(0.f, 0.f);
    fft_forward(ld, tw, threadIdx.x);
    const float2* Hc = (const float2*)Hf + (size_t)c * NFFT;
    for (int i = threadIdx.x; i < NFFT; i += 512) {
        float2 A = ld[i], Bv = Hc[i];
        ld[i] = make_float2(A.x * Bv.x - A.y * Bv.y, A.x * Bv.y + A.y * Bv.x);
    }
    fft_inverse(ld, tw, threadIdx.x);
    float dbc = Db[c];
    const float* x2 = x2s + (size_t)bc * LL;
    float* out = yg + (size_t)bc * LL;
    for (int i = threadIdx.x; i < LL; i += 512) {
        float yv = ld[i].x * (1.0f / NFFT) + v[i] * dbc;
        out[i] = yv * x2[i];
    }
}

// ---------------------------------------------------------------------------
extern "C" void kernel_launch(void* const* d_in, const int* in_sizes, int n_in,
                              void* d_out, int out_size, void* d_ws, size_t ws_size,
                              hipStream_t stream) {
    const int*   ids   = (const int*)  d_in[0];
    const float* emb   = (const float*)d_in[1];
    const float* ln1_g = (const float*)d_in[2];
    const float* ln1_b = (const float*)d_in[3];
    const float* Win   = (const float*)d_in[4];
    const float* bin_  = (const float*)d_in[5];
    const float* convw = (const float*)d_in[6];
    const float* convb = (const float*)d_in[7];
    const float* hflt  = (const float*)d_in[8];
    const float* Db    = (const float*)d_in[9];
    const float* Wout  = (const float*)d_in[10];
    const float* bout  = (const float*)d_in[11];
    const float* ln2_g = (const float*)d_in[12];
    const float* ln2_b = (const float*)d_in[13];
    const float* W1    = (const float*)d_in[14];
    const float* b1    = (const float*)d_in[15];
    const float* W2    = (const float*)d_in[16];
    const float* b2    = (const float*)d_in[17];
    const float* lnf_g = (const float*)d_in[18];
    const float* lnf_b = (const float*)d_in[19];

    char* p_ = (char*)d_ws;
    auto alloc = [&](size_t bytes) {
        char* r = p_; p_ += (bytes + 255) & ~(size_t)255; return r;
    };
    float* u   = (float*)alloc((size_t)BLD * 4);
    u16* zh    = (u16*)  alloc((size_t)BLD * 2);
    u16* zl    = (u16*)  alloc((size_t)BLD * 2);
    // union: pf (f32 3*BLD) | yg (f32 BLD) | hmid hi+lo (2 * BLH u16)
    char* uni  = alloc(2 * BLH * 2);      // 134.2 MB >= pf's 100.7 MB
    float* pf  = (float*)uni;
    float* yg  = (float*)uni;
    u16* hmh   = (u16*)uni;
    u16* hml   = hmh + BLH;
    float* vg  = (float*)alloc((size_t)BLD * 4);
    float* x2s = (float*)alloc((size_t)BLD * 4);
    u16* yh    = (u16*)  alloc((size_t)BLD * 2);
    u16* yl    = (u16*)  alloc((size_t)BLD * 2);
    float* Hf  = (float*)alloc((size_t)2 * DD * NFFT * 4);
    float* tw  = (float*)alloc((size_t)2 * NH * 4);
    u16* WtInH = (u16*)alloc((size_t)NLAYER * TD * DD * 2);
    u16* WtInL = (u16*)alloc((size_t)NLAYER * TD * DD * 2);
    u16* WtOutH= (u16*)alloc((size_t)NLAYER * DD * DD * 2);
    u16* WtOutL= (u16*)alloc((size_t)NLAYER * DD * DD * 2);
    u16* Wt1H  = (u16*)alloc((size_t)NLAYER * DD * HD * 2);
    u16* Wt1L  = (u16*)alloc((size_t)NLAYER * DD * HD * 2);
    u16* Wt2H  = (u16*)alloc((size_t)NLAYER * HD * DD * 2);
    u16* Wt2L  = (u16*)alloc((size_t)NLAYER * HD * DD * 2);

    twiddle_kernel<<<(NH + 255) / 256, 256, 0, stream>>>(tw);
    embed_kernel<<<(BLD + 255) / 256, 256, 0, stream>>>(ids, emb, u);
    wprep_kernel<<<dim3(TD / 64, DD / 64, NLAYER), 256, 0, stream>>>(
        Win, WtInH, WtInL, DD, TD, (long)DD * TD, (long)TD * DD);
    wprep_kernel<<<dim3(DD / 64, DD / 64, NLAYER), 256, 0, stream>>>(
        Wout, WtOutH, WtOutL, DD, DD, (long)DD * DD, (long)DD * DD);
    wprep_kernel<<<dim3(HD / 64, DD / 64, NLAYER), 256, 0, stream>>>(
        W1, Wt1H, Wt1L, DD, HD, (long)DD * HD, (long)DD * HD);
    wprep_kernel<<<dim3(DD / 64, HD / 64, NLAYER), 256, 0, stream>>>(
        W2, Wt2H, Wt2L, HD, DD, (long)HD * DD, (long)HD * DD);

    for (int l = 0; l < NLAYER; l++) {
        ln_kernel<1><<<BB * LL, 128, 0, stream>>>(u, zh, zl,
            ln1_g + l * DD, ln1_b + l * DD);

        // p = z @ Win + bin  -> f32 [B*L, 3D]
        mfma_gemm3<0, false><<<dim3(TD / 128, (BB * LL) / 128), 256, 0, stream>>>(
            zh, zl, WtInH + (size_t)l * TD * DD, WtInL + (size_t)l * TD * DD,
            bin_ + (size_t)l * TD, pf, nullptr, nullptr, BB * LL, TD, DD);

        conv_gate_kernel<<<dim3(LL / 64, DD / 64, BB), 256, 0, stream>>>(
            pf, convw + (size_t)l * TD * 3, convb + (size_t)l * TD, vg, x2s);

        hf_kernel<<<DD, 512, 0, stream>>>(hflt + (size_t)l * DD * LL, Hf, tw);

        fftconv_kernel<<<BB * DD, 512, 0, stream>>>(vg, x2s, Hf, Db + (size_t)l * DD, tw, yg);

        ytr_kernel<<<dim3(LL / 64, DD / 64, BB), 256, 0, stream>>>(yg, yh, yl);

        // u += y @ Wout + bout
        mfma_gemm3<2, false><<<dim3(DD / 128, (BB * LL) / 128), 256, 0, stream>>>(
            yh, yl, WtOutH + (size_t)l * DD * DD, WtOutL + (size_t)l * DD * DD,
            bout + (size_t)l * DD, u, nullptr, nullptr, BB * LL, DD, DD);

        ln_kernel<1><<<BB * LL, 128, 0, stream>>>(u, zh, zl,
            ln2_g + l * DD, ln2_b + l * DD);

        // hmid = gelu(z @ W1 + b1) -> bf16 hi/lo
        mfma_gemm3<1, true><<<dim3(HD / 128, (BB * LL) / 128), 256, 0, stream>>>(
            zh, zl, Wt1H + (size_t)l * DD * HD, Wt1L + (size_t)l * DD * HD,
            b1 + (size_t)l * HD, nullptr, hmh, hml, BB * LL, HD, DD);

        // u += hmid @ W2 + b2
        mfma_gemm3<2, false><<<dim3(DD / 128, (BB * LL) / 128), 256, 0, stream>>>(
            hmh, hml, Wt2H + (size_t)l * HD * DD, Wt2L + (size_t)l * HD * DD,
            b2 + (size_t)l * DD, u, nullptr, nullptr, BB * LL, DD, HD);
    }

    ln_kernel<0><<<BB * LL, 128, 0, stream>>>(u, (float*)d_out, nullptr, lnf_g, lnf_b);
}

// Round 4
// 5998.792 us; speedup vs baseline: 2.1964x; 1.1621x over previous
//
#include <hip/hip_runtime.h>
#include <hip/hip_bf16.h>
#include <math.h>

#define BB 2
#define LL 8192
#define DD 512
#define NLAYER 8
#define TD 1536   // 3*D
#define HD 2048   // 4*D
#define NFFT 16384
#define BLD (BB*LL*DD)
#define BLH ((size_t)BB*LL*HD)

typedef unsigned short u16;
typedef unsigned int   u32;
typedef __bf16 bf16x8 __attribute__((ext_vector_type(8)));
typedef float  f32x4  __attribute__((ext_vector_type(4)));

__device__ __forceinline__ u16 f2bf(float f) {
    union { float f; u32 u; } v; v.f = f;
    u32 r = v.u + 0x7FFF + ((v.u >> 16) & 1);   // RNE
    return (u16)(r >> 16);
}
__device__ __forceinline__ float bf2f(u16 h) {
    union { u32 u; float f; } v; v.u = (u32)h << 16; return v.f;
}

__device__ __forceinline__ void async_g2l_16(const u16* g, u16* l) {
    __builtin_amdgcn_global_load_lds(
        (const __attribute__((address_space(1))) void*)g,
        (__attribute__((address_space(3))) void*)l,
        16, 0, 0);
}

__device__ __forceinline__ float2 cmul(float2 a, float2 b) {
    return make_float2(a.x * b.x - a.y * b.y, a.x * b.y + a.y * b.x);
}
__device__ __forceinline__ float2 cmulc(float2 a, float2 b) {  // a*conj(b)
    return make_float2(a.x * b.x + a.y * b.y, a.y * b.x - a.x * b.y);
}
__device__ __forceinline__ float2 cadd(float2 a, float2 b) {
    return make_float2(a.x + b.x, a.y + b.y);
}
__device__ __forceinline__ float2 csub(float2 a, float2 b) {
    return make_float2(a.x - b.x, a.y - b.y);
}
// reverse 7 base-4 digits of a 14-bit index
__device__ __forceinline__ int drev14(int x) {
    return ((x & 3) << 12) | (((x >> 2) & 3) << 10) | (((x >> 4) & 3) << 8) |
           (((x >> 6) & 3) << 6) | (((x >> 8) & 3) << 4) | (((x >> 10) & 3) << 2) |
           ((x >> 12) & 3);
}

// ---------------- twiddle table: tw[k] = exp(-2*pi*i*k/NFFT), k in [0,N) ----
__global__ void twiddle_kernel(float* twf) {
    int k = blockIdx.x * 256 + threadIdx.x;
    if (k < NFFT) {
        double ang = -2.0 * M_PI * (double)k / (double)NFFT;
        twf[2 * k]     = (float)cos(ang);
        twf[2 * k + 1] = (float)sin(ang);
    }
}

// ---------------- embedding ------------------------------------------------
__global__ void embed_kernel(const int* __restrict__ ids,
                             const float* __restrict__ emb,
                             float* __restrict__ u) {
    int i = blockIdx.x * 256 + threadIdx.x;
    if (i < BLD) {
        int row = i >> 9;
        int d   = i & (DD - 1);
        u[i] = emb[ids[row] * DD + d];
    }
}

// ------------- weight prep: f32 [K,N] -> bf16 hi/lo [N,K] -------------------
__global__ __launch_bounds__(256)
void wprep_kernel(const float* __restrict__ W, u16* __restrict__ WtH,
                  u16* __restrict__ WtL, int K, int N, long srcStride, long dstStride) {
    __shared__ float t[64][65];
    const float* src = W + (size_t)blockIdx.z * srcStride;
    u16* dsth = WtH + (size_t)blockIdx.z * dstStride;
    u16* dstl = WtL + (size_t)blockIdx.z * dstStride;
    int n0 = blockIdx.x * 64, k0 = blockIdx.y * 64;
    int tc = threadIdx.x & 63, tr = threadIdx.x >> 6;
    for (int r = tr; r < 64; r += 4)
        t[r][tc] = src[(size_t)(k0 + r) * N + n0 + tc];
    __syncthreads();
    for (int r = tr; r < 64; r += 4) {
        float v = t[tc][r];
        u16 h = f2bf(v);
        dsth[(size_t)(n0 + r) * K + k0 + tc] = h;
        dstl[(size_t)(n0 + r) * K + k0 + tc] = f2bf(v - bf2f(h));
    }
}

// ---------------- layernorm (row length 512) -------------------------------
template<int MODE>   // 0: f32 out. 1: bf16 hi/lo planes.
__global__ __launch_bounds__(128)
void ln_kernel(const float* __restrict__ x, void* __restrict__ out,
               void* __restrict__ outL,
               const float* __restrict__ g, const float* __restrict__ b) {
    int row = blockIdx.x;
    const float4* xr = (const float4*)(x + (size_t)row * DD);
    int t = threadIdx.x;
    float4 v = xr[t];
    float s  = v.x + v.y + v.z + v.w;
    float ss = v.x * v.x + v.y * v.y + v.z * v.z + v.w * v.w;
    for (int off = 32; off; off >>= 1) {
        s  += __shfl_down(s, off);
        ss += __shfl_down(ss, off);
    }
    __shared__ float sm[4];
    if ((t & 63) == 0) { sm[(t >> 6) * 2] = s; sm[(t >> 6) * 2 + 1] = ss; }
    __syncthreads();
    float S = sm[0] + sm[2], SS = sm[1] + sm[3];
    float mu  = S * (1.0f / DD);
    float var = SS * (1.0f / DD) - mu * mu;
    float rs  = rsqrtf(var + 1e-5f);
    float4 gg = ((const float4*)g)[t];
    float4 bb = ((const float4*)b)[t];
    float o[4];
    o[0] = (v.x - mu) * rs * gg.x + bb.x;
    o[1] = (v.y - mu) * rs * gg.y + bb.y;
    o[2] = (v.z - mu) * rs * gg.z + bb.z;
    o[3] = (v.w - mu) * rs * gg.w + bb.w;
    if (MODE == 1) {
        u16 h[4], lo[4];
#pragma unroll
        for (int i = 0; i < 4; i++) {
            h[i]  = f2bf(o[i]);
            lo[i] = f2bf(o[i] - bf2f(h[i]));
        }
        uint2 ph, pl;
        ph.x = (u32)h[0] | ((u32)h[1] << 16);  ph.y = (u32)h[2] | ((u32)h[3] << 16);
        pl.x = (u32)lo[0] | ((u32)lo[1] << 16); pl.y = (u32)lo[2] | ((u32)lo[3] << 16);
        ((uint2*)((u16*)out  + (size_t)row * DD))[t] = ph;
        ((uint2*)((u16*)outL + (size_t)row * DD))[t] = pl;
    } else {
        float4 of = {o[0], o[1], o[2], o[3]};
        ((float4*)((float*)out + (size_t)row * DD))[t] = of;
    }
}

// ---------------- gelu (tanh approximation, JAX default) -------------------
__device__ __forceinline__ float gelu_f(float x) {
    float x3 = x * x * x;
    float t  = tanhf(0.79788456080286541f * (x + 0.044715f * x3));
    return 0.5f * x * (1.0f + t);
}

// ------- compensated bf16 MFMA GEMM: C = (Ah+Al) @ (Bh+Bl)^T + bias --------
template<int OUT, bool GELU>   // OUT 0: f32 store. 1: bf16 hi/lo. 2: f32 accum.
__global__ __launch_bounds__(256)
void mfma_gemm3(const u16* __restrict__ Ah, const u16* __restrict__ Al,
                const u16* __restrict__ Bh, const u16* __restrict__ Bl,
                const float* __restrict__ bias,
                float* __restrict__ Cf, u16* __restrict__ Ch, u16* __restrict__ Cl,
                int M, int N, int K) {
    __shared__ u16 AsH[128 * 32];
    __shared__ u16 AsL[128 * 32];
    __shared__ u16 BsH[128 * 32];
    __shared__ u16 BsL[128 * 32];
    int m0 = blockIdx.y * 128, n0 = blockIdx.x * 128;
    int tid = threadIdx.x;
    int w = tid >> 6, l = tid & 63;
    int wr = w >> 1, wc = w & 1;

    int ch0 = w * 2, ch1 = ch0 + 1;
    size_t offA0 = (size_t)(m0 + ch0 * 16 + (l >> 2)) * K + (l & 3) * 8;
    size_t offA1 = (size_t)(m0 + ch1 * 16 + (l >> 2)) * K + (l & 3) * 8;
    size_t offB0 = (size_t)(n0 + ch0 * 16 + (l >> 2)) * K + (l & 3) * 8;
    size_t offB1 = (size_t)(n0 + ch1 * 16 + (l >> 2)) * K + (l & 3) * 8;

    f32x4 acc[4][4] = {};
    int arow = wr * 64 + (l & 15);
    int brow = wc * 64 + (l & 15);
    int kc   = (l >> 4) * 8;

    for (int k0 = 0; k0 < K; k0 += 32) {
        async_g2l_16(Ah + offA0 + k0, &AsH[ch0 * 512]);
        async_g2l_16(Ah + offA1 + k0, &AsH[ch1 * 512]);
        async_g2l_16(Al + offA0 + k0, &AsL[ch0 * 512]);
        async_g2l_16(Al + offA1 + k0, &AsL[ch1 * 512]);
        async_g2l_16(Bh + offB0 + k0, &BsH[ch0 * 512]);
        async_g2l_16(Bh + offB1 + k0, &BsH[ch1 * 512]);
        async_g2l_16(Bl + offB0 + k0, &BsL[ch0 * 512]);
        async_g2l_16(Bl + offB1 + k0, &BsL[ch1 * 512]);
        __syncthreads();
        bf16x8 ah[4], al[4], bh[4], bl[4];
#pragma unroll
        for (int i = 0; i < 4; i++) {
            ah[i] = *(const bf16x8*)&AsH[(arow + i * 16) * 32 + kc];
            al[i] = *(const bf16x8*)&AsL[(arow + i * 16) * 32 + kc];
            bh[i] = *(const bf16x8*)&BsH[(brow + i * 16) * 32 + kc];
            bl[i] = *(const bf16x8*)&BsL[(brow + i * 16) * 32 + kc];
        }
#pragma unroll
        for (int mi = 0; mi < 4; mi++)
#pragma unroll
            for (int ni = 0; ni < 4; ni++) {
                acc[mi][ni] = __builtin_amdgcn_mfma_f32_16x16x32_bf16(
                    ah[mi], bh[ni], acc[mi][ni], 0, 0, 0);
                acc[mi][ni] = __builtin_amdgcn_mfma_f32_16x16x32_bf16(
                    al[mi], bh[ni], acc[mi][ni], 0, 0, 0);
                acc[mi][ni] = __builtin_amdgcn_mfma_f32_16x16x32_bf16(
                    ah[mi], bl[ni], acc[mi][ni], 0, 0, 0);
            }
        __syncthreads();
    }

    int lr = l >> 4, lc = l & 15;
#pragma unroll
    for (int mi = 0; mi < 4; mi++) {
#pragma unroll
        for (int ni = 0; ni < 4; ni++) {
            int col = n0 + wc * 64 + ni * 16 + lc;
            float bv = bias[col];
            int rowb = m0 + wr * 64 + mi * 16 + lr * 4;
#pragma unroll
            for (int r = 0; r < 4; r++) {
                float v = acc[mi][ni][r] + bv;
                if (GELU) v = gelu_f(v);
                size_t off = (size_t)(rowb + r) * N + col;
                if (OUT == 0) {
                    Cf[off] = v;
                } else if (OUT == 1) {
                    u16 h = f2bf(v);
                    Ch[off] = h;
                    Cl[off] = f2bf(v - bf2f(h));
                } else {
                    Cf[off] += v;
                }
            }
        }
    }
}

// ---------------- short conv (k=3 causal) + gating + transpose -------------
__global__ __launch_bounds__(256)
void conv_gate_kernel(const float* __restrict__ p, const float* __restrict__ cw,
                      const float* __restrict__ cb, float* __restrict__ vg,
                      float* __restrict__ x2s) {
    __shared__ float tvg[64][65];
    __shared__ float tx2[64][65];
    int b = blockIdx.z, c0 = blockIdx.y * 64, l0 = blockIdx.x * 64;
    int tc = threadIdx.x & 63, tr = threadIdx.x >> 6;
    const float* pb = p + (size_t)b * LL * TD;
    int cx2 = c0 + tc;
    int cx1 = DD + c0 + tc;
    int cv  = 2 * DD + c0 + tc;
    float w20 = cw[cx2 * 3], w21 = cw[cx2 * 3 + 1], w22 = cw[cx2 * 3 + 2], bx2 = cb[cx2];
    float w10 = cw[cx1 * 3], w11 = cw[cx1 * 3 + 1], w12 = cw[cx1 * 3 + 2], bx1 = cb[cx1];
    float wv0 = cw[cv * 3],  wv1 = cw[cv * 3 + 1],  wv2 = cw[cv * 3 + 2],  bv  = cb[cv];
    for (int r = tr; r < 64; r += 4) {
        int l = l0 + r;
        size_t o0 = (size_t)l * TD;
        float p2a = (l >= 2) ? pb[o0 - 2 * TD + cx2] : 0.f;
        float p1a = (l >= 1) ? pb[o0 - TD + cx2] : 0.f;
        float p0a = pb[o0 + cx2];
        float p2b = (l >= 2) ? pb[o0 - 2 * TD + cx1] : 0.f;
        float p1b = (l >= 1) ? pb[o0 - TD + cx1] : 0.f;
        float p0b = pb[o0 + cx1];
        float p2c = (l >= 2) ? pb[o0 - 2 * TD + cv] : 0.f;
        float p1c = (l >= 1) ? pb[o0 - TD + cv] : 0.f;
        float p0c = pb[o0 + cv];
        float x2v = w20 * p2a + w21 * p1a + w22 * p0a + bx2;
        float x1v = w10 * p2b + w11 * p1b + w12 * p0b + bx1;
        float vv  = wv0 * p2c + wv1 * p1c + wv2 * p0c + bv;
        tx2[r][tc] = x2v;
        tvg[r][tc] = vv * x1v;
    }
    __syncthreads();
    for (int r = tr; r < 64; r += 4) {
        size_t o = ((size_t)b * DD + c0 + r) * LL + l0 + tc;
        vg[o]  = tvg[tc][r];
        x2s[o] = tx2[tc][r];
    }
}

// -------- y transpose: f32 [B,D,L] -> bf16 hi/lo [B*L, D] ------------------
__global__ __launch_bounds__(256)
void ytr_kernel(const float* __restrict__ yg, u16* __restrict__ yh,
                u16* __restrict__ yl) {
    __shared__ float t[64][65];
    int b = blockIdx.z, c0 = blockIdx.y * 64, l0 = blockIdx.x * 64;
    int tc = threadIdx.x & 63, tr = threadIdx.x >> 6;
    for (int r = tr; r < 64; r += 4)
        t[r][tc] = yg[((size_t)b * DD + c0 + r) * LL + l0 + tc];
    __syncthreads();
    for (int r = tr; r < 64; r += 4) {
        float v = t[tc][r];
        u16 h = f2bf(v);
        size_t o = ((size_t)(b * LL + l0 + r)) * DD + c0 + tc;
        yh[o] = h;
        yl[o] = f2bf(v - bf2f(h));
    }
}

// ---------------- radix-4 FFT (16384 = 4^7, in LDS) ------------------------
// Forward DIF: natural in -> base-4-digit-reversed out.
__device__ __forceinline__ void fft4_fwd(float2* ld, const float2* __restrict__ tw, int tid) {
    for (int s = 0; s < 7; s++) {
        int lm = 14 - 2 * s, lq = lm - 2;
        int Q = 1 << lq;
        __syncthreads();
        for (int g = tid; g < NFFT / 4; g += 512) {
            int j = g & (Q - 1);
            int base = ((g >> lq) << lm) + j;
            float2 x0 = ld[base], x1 = ld[base + Q], x2 = ld[base + 2 * Q], x3 = ld[base + 3 * Q];
            float2 a = cadd(x0, x2), b = csub(x0, x2);
            float2 c = cadd(x1, x3), d = csub(x1, x3);
            float2 mid = make_float2(d.y, -d.x);          // -i*d
            float2 u0 = cadd(a, c);
            float2 u1 = cadd(b, mid);
            float2 u2 = csub(a, c);
            float2 u3 = csub(b, mid);
            int e = j << (2 * s);
            if (e) {                                       // j==0 -> all twiddles 1
                u1 = cmul(u1, tw[e]);
                u2 = cmul(u2, tw[2 * e]);
                u3 = cmul(u3, tw[3 * e]);
            }
            ld[base] = u0; ld[base + Q] = u1; ld[base + 2 * Q] = u2; ld[base + 3 * Q] = u3;
        }
    }
    __syncthreads();
}

// Inverse DIT: digit-reversed in -> natural out, conj twiddles (no 1/N).
__device__ __forceinline__ void fft4_inv(float2* ld, const float2* __restrict__ tw, int tid) {
    for (int s = 6; s >= 0; s--) {
        int lm = 14 - 2 * s, lq = lm - 2;
        int Q = 1 << lq;
        __syncthreads();
        for (int g = tid; g < NFFT / 4; g += 512) {
            int j = g & (Q - 1);
            int base = ((g >> lq) << lm) + j;
            int e = j << (2 * s);
            float2 v0 = ld[base];
            float2 v1 = ld[base + Q], v2 = ld[base + 2 * Q], v3 = ld[base + 3 * Q];
            if (e) {
                v1 = cmulc(v1, tw[e]);
                v2 = cmulc(v2, tw[2 * e]);
                v3 = cmulc(v3, tw[3 * e]);
            }
            float2 a = cadd(v0, v2), b = csub(v0, v2);
            float2 c = cadd(v1, v3), d = csub(v1, v3);
            float2 id = make_float2(-d.y, d.x);           // +i*d
            ld[base]         = cadd(a, c);
            ld[base + Q]     = cadd(b, id);
            ld[base + 2 * Q] = csub(a, c);
            ld[base + 3 * Q] = csub(b, id);
        }
    }
    __syncthreads();
}

// ---------------- filter FFT, 2 channels packed per block ------------------
// Outputs separated spectra F1,F2 at digit-reversed positions.
__global__ __launch_bounds__(512)
void hf_kernel(const float* __restrict__ h, float2* __restrict__ Hf1,
               float2* __restrict__ Hf2, const float* __restrict__ twf) {
    __shared__ float2 ld[NFFT];  // 128 KiB
    int cp = blockIdx.x;          // channel pair
    const float* h1 = h + (size_t)(2 * cp) * LL;
    const float* h2 = h + (size_t)(2 * cp + 1) * LL;
    const float2* tw = (const float2*)twf;
    int tid = threadIdx.x;
    for (int i = tid; i < LL; i += 512) ld[i] = make_float2(h1[i], h2[i]);
    for (int i = LL + tid; i < NFFT; i += 512) ld[i] = make_float2(0.f, 0.f);
    fft4_fwd(ld, tw, tid);
    float2* o1 = Hf1 + (size_t)cp * NFFT;
    float2* o2 = Hf2 + (size_t)cp * NFFT;
    for (int p = tid; p < NFFT; p += 512) {
        int k  = drev14(p);
        int kc = (NFFT - k) & (NFFT - 1);
        if (k > kc) continue;
        int pc = drev14(kc);
        float2 Zk = ld[p], Zc = ld[pc];
        float2 F1 = make_float2(0.5f * (Zk.x + Zc.x), 0.5f * (Zk.y - Zc.y));
        float2 F2 = make_float2(0.5f * (Zk.y + Zc.y), 0.5f * (Zc.x - Zk.x));
        o1[p]  = F1;
        o2[p]  = F2;
        o1[pc] = make_float2(F1.x, -F1.y);
        o2[pc] = make_float2(F2.x, -F2.y);
    }
}

// ------- FFT convolution, 2 channels per block + skip + output gate --------
__global__ __launch_bounds__(512)
void fftconv_kernel(const float* __restrict__ vg, const float* __restrict__ x2s,
                    const float2* __restrict__ Hf1, const float2* __restrict__ Hf2,
                    const float* __restrict__ Db, const float* __restrict__ twf,
                    float* __restrict__ yg) {
    __shared__ float2 ld[NFFT];  // 128 KiB
    int bcp = blockIdx.x;                 // b * (DD/2) + cp
    int b = bcp >> 8, cp = bcp & 255;
    int c1 = 2 * cp, c2 = 2 * cp + 1;
    const float* v1 = vg + ((size_t)b * DD + c1) * LL;
    const float* v2 = vg + ((size_t)b * DD + c2) * LL;
    const float2* tw = (const float2*)twf;
    int tid = threadIdx.x;
    for (int i = tid; i < LL; i += 512) ld[i] = make_float2(v1[i], v2[i]);
    for (int i = LL + tid; i < NFFT; i += 512) ld[i] = make_float2(0.f, 0.f);
    fft4_fwd(ld, tw, tid);
    const float2* H1 = Hf1 + (size_t)cp * NFFT;
    const float2* H2 = Hf2 + (size_t)cp * NFFT;
    for (int p = tid; p < NFFT; p += 512) {
        int k  = drev14(p);
        int kc = (NFFT - k) & (NFFT - 1);
        if (k > kc) continue;
        int pc = drev14(kc);
        float2 Zk = ld[p], Zc = ld[pc];
        float2 F1 = make_float2(0.5f * (Zk.x + Zc.x), 0.5f * (Zk.y - Zc.y));
        float2 F2 = make_float2(0.5f * (Zk.y + Zc.y), 0.5f * (Zc.x - Zk.x));
        float2 c1v = cmul(F1, H1[p]);
        float2 c2v = cmul(F2, H2[p]);
        ld[p]  = make_float2(c1v.x - c2v.y, c1v.y + c2v.x);   // W[k]  = c1 + i*c2
        ld[pc] = make_float2(c1v.x + c2v.y, c2v.x - c1v.y);   // W[k'] = conj(c1) + i*conj(c2)
    }
    fft4_inv(ld, tw, tid);
    float db1 = Db[c1], db2 = Db[c2];
    const float* x21 = x2s + ((size_t)b * DD + c1) * LL;
    const float* x22 = x2s + ((size_t)b * DD + c2) * LL;
    float* o1 = yg + ((size_t)b * DD + c1) * LL;
    float* o2 = yg + ((size_t)b * DD + c2) * LL;
    for (int i = tid; i < LL; i += 512) {
        float y1 = ld[i].x * (1.0f / NFFT) + v1[i] * db1;
        float y2 = ld[i].y * (1.0f / NFFT) + v2[i] * db2;
        o1[i] = y1 * x21[i];
        o2[i] = y2 * x22[i];
    }
}

// ---------------------------------------------------------------------------
extern "C" void kernel_launch(void* const* d_in, const int* in_sizes, int n_in,
                              void* d_out, int out_size, void* d_ws, size_t ws_size,
                              hipStream_t stream) {
    const int*   ids   = (const int*)  d_in[0];
    const float* emb   = (const float*)d_in[1];
    const float* ln1_g = (const float*)d_in[2];
    const float* ln1_b = (const float*)d_in[3];
    const float* Win   = (const float*)d_in[4];
    const float* bin_  = (const float*)d_in[5];
    const float* convw = (const float*)d_in[6];
    const float* convb = (const float*)d_in[7];
    const float* hflt  = (const float*)d_in[8];
    const float* Db    = (const float*)d_in[9];
    const float* Wout  = (const float*)d_in[10];
    const float* bout  = (const float*)d_in[11];
    const float* ln2_g = (const float*)d_in[12];
    const float* ln2_b = (const float*)d_in[13];
    const float* W1    = (const float*)d_in[14];
    const float* b1    = (const float*)d_in[15];
    const float* W2    = (const float*)d_in[16];
    const float* b2    = (const float*)d_in[17];
    const float* lnf_g = (const float*)d_in[18];
    const float* lnf_b = (const float*)d_in[19];

    char* p_ = (char*)d_ws;
    auto alloc = [&](size_t bytes) {
        char* r = p_; p_ += (bytes + 255) & ~(size_t)255; return r;
    };
    float* u   = (float*)alloc((size_t)BLD * 4);
    u16* zh    = (u16*)  alloc((size_t)BLD * 2);
    u16* zl    = (u16*)  alloc((size_t)BLD * 2);
    char* uni  = alloc(2 * BLH * 2);      // pf (f32 3*BLD) | yg (f32 BLD) | hmid hi/lo
    float* pf  = (float*)uni;
    float* yg  = (float*)uni;
    u16* hmh   = (u16*)uni;
    u16* hml   = hmh + BLH;
    float* vg  = (float*)alloc((size_t)BLD * 4);
    float* x2s = (float*)alloc((size_t)BLD * 4);
    u16* yh    = (u16*)  alloc((size_t)BLD * 2);
    u16* yl    = (u16*)  alloc((size_t)BLD * 2);
    float2* Hf1 = (float2*)alloc((size_t)(DD / 2) * NFFT * 8);
    float2* Hf2 = (float2*)alloc((size_t)(DD / 2) * NFFT * 8);
    float* tw  = (float*)alloc((size_t)2 * NFFT * 4);
    u16* WtInH = (u16*)alloc((size_t)NLAYER * TD * DD * 2);
    u16* WtInL = (u16*)alloc((size_t)NLAYER * TD * DD * 2);
    u16* WtOutH= (u16*)alloc((size_t)NLAYER * DD * DD * 2);
    u16* WtOutL= (u16*)alloc((size_t)NLAYER * DD * DD * 2);
    u16* Wt1H  = (u16*)alloc((size_t)NLAYER * DD * HD * 2);
    u16* Wt1L  = (u16*)alloc((size_t)NLAYER * DD * HD * 2);
    u16* Wt2H  = (u16*)alloc((size_t)NLAYER * HD * DD * 2);
    u16* Wt2L  = (u16*)alloc((size_t)NLAYER * HD * DD * 2);

    twiddle_kernel<<<(NFFT + 255) / 256, 256, 0, stream>>>(tw);
    embed_kernel<<<(BLD + 255) / 256, 256, 0, stream>>>(ids, emb, u);
    wprep_kernel<<<dim3(TD / 64, DD / 64, NLAYER), 256, 0, stream>>>(
        Win, WtInH, WtInL, DD, TD, (long)DD * TD, (long)TD * DD);
    wprep_kernel<<<dim3(DD / 64, DD / 64, NLAYER), 256, 0, stream>>>(
        Wout, WtOutH, WtOutL, DD, DD, (long)DD * DD, (long)DD * DD);
    wprep_kernel<<<dim3(HD / 64, DD / 64, NLAYER), 256, 0, stream>>>(
        W1, Wt1H, Wt1L, DD, HD, (long)DD * HD, (long)DD * HD);
    wprep_kernel<<<dim3(DD / 64, HD / 64, NLAYER), 256, 0, stream>>>(
        W2, Wt2H, Wt2L, HD, DD, (long)HD * DD, (long)HD * DD);

    for (int l = 0; l < NLAYER; l++) {
        ln_kernel<1><<<BB * LL, 128, 0, stream>>>(u, zh, zl,
            ln1_g + l * DD, ln1_b + l * DD);

        mfma_gemm3<0, false><<<dim3(TD / 128, (BB * LL) / 128), 256, 0, stream>>>(
            zh, zl, WtInH + (size_t)l * TD * DD, WtInL + (size_t)l * TD * DD,
            bin_ + (size_t)l * TD, pf, nullptr, nullptr, BB * LL, TD, DD);

        conv_gate_kernel<<<dim3(LL / 64, DD / 64, BB), 256, 0, stream>>>(
            pf, convw + (size_t)l * TD * 3, convb + (size_t)l * TD, vg, x2s);

        hf_kernel<<<DD / 2, 512, 0, stream>>>(hflt + (size_t)l * DD * LL, Hf1, Hf2, tw);

        fftconv_kernel<<<BB * (DD / 2), 512, 0, stream>>>(
            vg, x2s, Hf1, Hf2, Db + (size_t)l * DD, tw, yg);

        ytr_kernel<<<dim3(LL / 64, DD / 64, BB), 256, 0, stream>>>(yg, yh, yl);

        mfma_gemm3<2, false><<<dim3(DD / 128, (BB * LL) / 128), 256, 0, stream>>>(
            yh, yl, WtOutH + (size_t)l * DD * DD, WtOutL + (size_t)l * DD * DD,
            bout + (size_t)l * DD, u, nullptr, nullptr, BB * LL, DD, DD);

        ln_kernel<1><<<BB * LL, 128, 0, stream>>>(u, zh, zl,
            ln2_g + l * DD, ln2_b + l * DD);

        mfma_gemm3<1, true><<<dim3(HD / 128, (BB * LL) / 128), 256, 0, stream>>>(
            zh, zl, Wt1H + (size_t)l * DD * HD, Wt1L + (size_t)l * DD * HD,
            b1 + (size_t)l * HD, nullptr, hmh, hml, BB * LL, HD, DD);

        mfma_gemm3<2, false><<<dim3(DD / 128, (BB * LL) / 128), 256, 0, stream>>>(
            hmh, hml, Wt2H + (size_t)l * HD * DD, Wt2L + (size_t)l * HD * DD,
            b2 + (size_t)l * DD, u, nullptr, nullptr, BB * LL, DD, HD);
    }

    ln_kernel<0><<<BB * LL, 128, 0, stream>>>(u, (float*)d_out, nullptr, lnf_g, lnf_b);
}